// Round 5
// baseline (166.958 us; speedup 1.0000x reference)
//
#include <hip/hip_runtime.h>
#include <math.h>

#define ALPHA 0.2f

// Problem constants (fixed by reference)
#define NB 4
#define TT 24
#define VV 32
#define HW 256   // 16*16

// ---------------------------------------------------------------------------
// Single kernel, 96 blocks = (n,t), 512 threads, NO cross-block communication
// and NO global scratch (avoids the ~50us agent-scope L2 drain measured in
// rounds 3/4 for any ws-mediated handoff, and the end-of-kernel flush of
// 13 MB dirty scratch in the round-2 two-kernel version).
//
// Per block:
//   E-trick: E[v][tt] = sum_p sum_t' h[p,t',v] * C[p,t',bin], where
//   C[p][t'][side,half] = sum_t a[q(p,t)]*W[t',t]; each p spans <=2 tt bins,
//   so redundant per-block E costs ~1 MFLOP instead of a full Wh recompute.
//   Also computes own-t Wh column into LDS during the same h pass.
//   Then adj_norm(B), softmax slice for own t, MT = adjn^T att_t, output.
// ---------------------------------------------------------------------------
__global__ __launch_bounds__(512) void gat_one(
    const float* __restrict__ h, const float* __restrict__ Wp,
    const float* __restrict__ ap, const float* __restrict__ Bp,
    float* __restrict__ out)
{
  __shared__ float WL[576];      // W[t'][t]
  __shared__ float aL[512];
  __shared__ float EiL[832];     // [v][26] (bins 0..24 used)
  __shared__ float EjL[832];
  __shared__ float WhOwnL[8192]; // [p][v] for own t
  __shared__ float OVL[3136];    // tile phase: cL[4][32][24]; epilogue: adjw/attL/MT
  __shared__ float dinvL[32];
  __shared__ float redmn[8], redmx[8];
  __shared__ float smn, smx;

  const int b   = blockIdx.x;
  const int n   = b / 24, t = b - n * 24;
  const int tid = threadIdx.x;
  const int v   = tid & 31;
  const int g   = tid >> 5;      // 0..15

  for (int idx = tid; idx < 576; idx += 512) WL[idx] = Wp[idx];
  for (int idx = tid; idx < 512; idx += 512) aL[idx] = ap[idx];
  for (int idx = tid; idx < 832; idx += 512) { EiL[idx] = 0.f; EjL[idx] = 0.f; }
  __syncthreads();

  float* cL = OVL;  // [sh][pl][t'] : sh = side*2+half, 4*32*24 = 3072 floats

  // -------- h pass: 8 tiles of 32 p --------
  for (int tile = 0; tile < 8; ++tile) {
    const int p0 = tile * 32;

    // prefetch this thread's two h rows (independent of cL — overlaps c-compute)
    const int pA = p0 + g, pB = p0 + g + 16;
    float hA[24], hB[24];
    {
      const float* hpA = h + ((size_t)(n * HW + pA) * TT) * VV + v;
      const float* hpB = h + ((size_t)(n * HW + pB) * TT) * VV + v;
      #pragma unroll
      for (int t2 = 0; t2 < 24; ++t2) { hA[t2] = hpA[t2 * 32]; hB[t2] = hpB[t2 * 32]; }
    }

    __syncthreads();   // previous tile's cL readers done

    // C coefficients for this tile: 3072 entries, 6 per thread
    for (int e = tid; e < 3072; e += 512) {
      const int sh  = e / 768;            // 0:i-lo 1:i-hi 2:j-lo 3:j-hi
      const int rem = e - sh * 768;
      const int pl  = rem / 24;
      const int tp  = rem - pl * 24;      // t'
      const int p   = p0 + pl;
      const int hh  = p >> 4, w = p & 15;
      const int q0  = hh * 768 + w * 24 + ((sh & 2) ? 384 : 0);
      const int tt0 = q0 >> 9;
      int s = (tt0 + 1) * 512 - q0; if (s > 24) s = 24;   // split point
      const int lo = (sh & 1) ? s : 0;
      const int hi = (sh & 1) ? 24 : s;
      float c = 0.f;
      for (int t2 = lo; t2 < hi; ++t2) c += aL[(q0 + t2) & 511] * WL[tp * 24 + t2];
      cL[e] = c;
    }
    __syncthreads();   // cL ready

    // dots: E contributions (2 bins per side) + own-t Wh, for 2 p per thread
#define DOP(HR, PL) {                                                      \
      const int p    = p0 + (PL);                                          \
      const int hh   = p >> 4, w = p & 15;                                 \
      const int qi0  = hh * 768 + w * 24;                                  \
      const int tti0 = qi0 >> 9, ttj0 = (qi0 + 384) >> 9;                  \
      const float* c0 = &cL[(PL) * 24];                                    \
      const float* c1 = &cL[768  + (PL) * 24];                             \
      const float* c2 = &cL[1536 + (PL) * 24];                             \
      const float* c3 = &cL[2304 + (PL) * 24];                             \
      float d0 = 0.f, d1 = 0.f, d2 = 0.f, d3 = 0.f, wh = 0.f;              \
      _Pragma("unroll")                                                    \
      for (int t2 = 0; t2 < 24; ++t2) {                                    \
        const float x = HR[t2];                                            \
        d0 += x * c0[t2]; d1 += x * c1[t2];                                \
        d2 += x * c2[t2]; d3 += x * c3[t2];                                \
        wh += x * WL[t2 * 24 + t];                                         \
      }                                                                    \
      WhOwnL[p * 32 + v] = wh;                                            \
      atomicAdd(&EiL[v * 26 + tti0],     d0);                              \
      atomicAdd(&EiL[v * 26 + tti0 + 1], d1);                              \
      atomicAdd(&EjL[v * 26 + ttj0],     d2);                              \
      atomicAdd(&EjL[v * 26 + ttj0 + 1], d3); }

    DOP(hA, g)
    DOP(hB, (g + 16))
#undef DOP
  }

  __syncthreads();   // EiL/EjL/WhOwnL complete; cL region free for epilogue

  float* adjw = OVL;          // [i*32+j] -> adj_norm in place
  float* attL = OVL + 1024;   // [i*32+j] for own t
  float* MT   = OVL + 2048;   // [j*32+v]

  // --- adjacency load + block min/max ---
  float lmn = 1e30f, lmx = -1e30f;
  for (int o = tid; o < 1024; o += 512) {
    const int i = o >> 5, j = o & 31;
    const float x = Bp[o] + 1e-6f + (i == j ? 1.f : 0.f);
    adjw[o] = x;
    lmn = fminf(lmn, x); lmx = fmaxf(lmx, x);
  }
  #pragma unroll
  for (int off = 32; off > 0; off >>= 1) {
    lmn = fminf(lmn, __shfl_down(lmn, off));
    lmx = fmaxf(lmx, __shfl_down(lmx, off));
  }
  if ((tid & 63) == 0) { redmn[tid >> 6] = lmn; redmx[tid >> 6] = lmx; }
  __syncthreads();

  if (tid == 0) {
    float a0 = redmn[0], b0 = redmx[0];
    #pragma unroll
    for (int k = 1; k < 8; ++k) { a0 = fminf(a0, redmn[k]); b0 = fmaxf(b0, redmx[k]); }
    smn = a0; smx = b0;
  }
  __syncthreads();

  const float rs = 1.f / (smx - smn);
  for (int o = tid; o < 1024; o += 512) adjw[o] = (adjw[o] - smn) * rs;
  __syncthreads();

  if (tid < 32) {
    float s = 0.f;
    #pragma unroll
    for (int j = 0; j < 32; ++j) s += adjw[tid * 32 + j];
    dinvL[tid] = rsqrtf(s);
  }
  __syncthreads();

  // finalize adj_norm in place; compute own-t att slice in the same phase
  for (int o = tid; o < 1024; o += 512) {
    const int i = o >> 5, j = o & 31;
    adjw[o] = adjw[o] * dinvL[i] * dinvL[j];
  }
  for (int pair = tid; pair < 1024; pair += 512) {
    const int i = pair >> 5, j = pair & 31;
    const float* Ei = &EiL[i * 26];
    const float* Ej = &EjL[j * 26];
    float ev[24];
    float mx = -1e30f;
    #pragma unroll
    for (int t2 = 0; t2 < 24; ++t2) {
      float x = Ei[t2] + Ej[t2];
      x = x > 0.f ? x : ALPHA * x;          // LeakyReLU
      ev[t2] = x; mx = fmaxf(mx, x);
    }
    float s = 0.f;
    #pragma unroll
    for (int t2 = 0; t2 < 24; ++t2) { const float e = __expf(ev[t2] - mx); ev[t2] = e; s += e; }
    attL[pair] = ev[t] / s;
  }
  __syncthreads();

  // MT[j,v] = sum_i adjn[i,v] * att[i,j]
  for (int o = tid; o < 1024; o += 512) {
    const int j = o >> 5, vv2 = o & 31;
    float s = 0.f;
    #pragma unroll
    for (int i2 = 0; i2 < 32; ++i2) s += adjw[i2 * 32 + vv2] * attL[i2 * 32 + j];
    MT[o] = s;
  }
  __syncthreads();

  // out[p, t, v] = sigmoid(elu( sum_j WhOwn[p,j] * MT[j,v] ))
  float mv[32];
  #pragma unroll
  for (int jj = 0; jj < 32; ++jj) mv[jj] = MT[jj * 32 + v];

  float* outg = out + (size_t)n * HW * TT * VV + (size_t)t * VV + v;
  #pragma unroll 4
  for (int k = 0; k < 16; ++k) {
    const int p = (g << 4) + k;
    const float4* wr = (const float4*)&WhOwnL[p * 32];   // broadcast b128 reads
    float accv = 0.f;
    #pragma unroll
    for (int q = 0; q < 8; ++q) {
      float4 w4 = wr[q];
      accv += w4.x * mv[q*4+0] + w4.y * mv[q*4+1] + w4.z * mv[q*4+2] + w4.w * mv[q*4+3];
    }
    const float e  = accv > 0.f ? accv : (__expf(accv) - 1.f);  // ELU(alpha=1)
    const float sg = 1.f / (1.f + __expf(-e));                  // sigmoid
    outg[(size_t)p * TT * VV] = sg;
  }
}

// ---------------------------------------------------------------------------
extern "C" void kernel_launch(void* const* d_in, const int* in_sizes, int n_in,
                              void* d_out, int out_size, void* d_ws, size_t ws_size,
                              hipStream_t stream) {
  const float* h  = (const float*)d_in[0];   // (4,16,16,24,32) f32
  const float* Wp = (const float*)d_in[1];   // (24,24)
  const float* ap = (const float*)d_in[2];   // (512,1)
  const float* Bp = (const float*)d_in[3];   // (32,32)
  float* out = (float*)d_out;                // (4,16,16,24,32) f32
  (void)d_ws; (void)ws_size;                 // no scratch: no L2-flush tax

  hipLaunchKernelGGL(gat_one, dim3(NB * TT), dim3(512), 0, stream,
                     h, Wp, ap, Bp, out);
}

// Round 6
// 90.860 us; speedup vs baseline: 1.8375x; 1.8375x over previous
//
#include <hip/hip_runtime.h>
#include <math.h>

#define ALPHA 0.2f

// Problem constants (fixed by reference)
#define NB 4
#define TT 24
#define VV 32
#define HW 256   // 16*16

// ---------------------------------------------------------------------------
// Single kernel, 96 blocks = (n,t), 1024 threads = (s:2, hh:16, v:32).
// No cross-block communication, no global scratch (rounds 3/4 measured ~50us
// for any ws-mediated handoff; round 5 measured 4.5M LDS-conflict cycles for
// per-tile LDS atomics — both avoided here).
//
// E-trick: E[v][tt] = sum_p sum_t' h[p,t',v] * C[p,t',half], where the C
// table depends on p only via (hh&1, w) -> 3072 floats computed ONCE per
// block. For fixed hh all 16 w hit bins {B,B+1,B+2} per side -> E partials
// accumulate in 6 registers, 6 one-shot LDS atomics per thread at the end.
// Own-t Wh column computed in the same h pass. Then adj_norm(B), softmax
// slice for own t, MT = adjn^T att_t, output GEMM + elu + sigmoid.
// ---------------------------------------------------------------------------
__global__ __launch_bounds__(1024) void gat_one(
    const float* __restrict__ h, const float* __restrict__ Wp,
    const float* __restrict__ ap, const float* __restrict__ Bp,
    float* __restrict__ out)
{
  __shared__ __align__(16) float WL[576];     // W[t'][t]
  __shared__ __align__(16) float aL[512];
  __shared__ __align__(16) float Ctab[3072];  // [(side*2+par)*2+half][w][t']; epilogue overlay
  __shared__ __align__(16) float WhOwnL[8192];// [p][v] for own t
  __shared__ float EiL[832];                  // [v][26] bins
  __shared__ float EjL[832];
  __shared__ float dinvL[32];
  __shared__ float redmn[16], redmx[16];
  __shared__ float smn, smx;

  const int b   = blockIdx.x;
  const int n   = b / TT, t = b - n * TT;
  const int tid = threadIdx.x;
  const int v   = tid & 31;
  const int hh  = (tid >> 5) & 15;
  const int s   = tid >> 9;        // 0 or 1 (w-half)
  const int par = hh & 1;

  for (int i = tid; i < 576; i += 1024) WL[i] = Wp[i];
  for (int i = tid; i < 512; i += 1024) aL[i] = ap[i];
  for (int i = tid; i < 832; i += 1024) { EiL[i] = 0.f; EjL[i] = 0.f; }
  __syncthreads();

  // own-t W column in registers
  float wcol[24];
  #pragma unroll
  for (int tp = 0; tp < 24; ++tp) wcol[tp] = WL[tp * 24 + t];

  // C table, once per block: c(cls,half,w)[t'] = sum_{t in half-range} a[(r+t)&511]*W[t',t]
  // r = (par*256 + side*384 + w*24) mod 512 ; crossing at t = 512-r.
  for (int e = tid; e < 3072; e += 1024) {
    const int cls  = e / 768;            // (side<<1)|par
    const int rem  = e - cls * 768;
    const int half = rem / 384;
    const int rem2 = rem - half * 384;
    const int w    = rem2 / 24;
    const int tp   = rem2 - w * 24;
    const int side = cls >> 1, pr = cls & 1;
    const int r    = (pr * 256 + side * 384 + w * 24) & 511;
    int sc = 512 - r; if (sc > 24) sc = 24;
    const int lo = half ? sc : 0;
    const int hi = half ? 24 : sc;
    float c = 0.f;
    for (int tq = lo; tq < hi; ++tq) c += aL[(r + tq) & 511] * WL[tp * 24 + tq];
    Ctab[e] = c;
  }
  __syncthreads();

  // ---------------- main h pass ----------------
  const int bi0 = (768 * hh) >> 9;          // side-i base bin for this hh
  const int bj0 = (768 * hh + 384) >> 9;    // side-j base bin
  float ei0 = 0.f, ei1 = 0.f, ei2 = 0.f;
  float ej0 = 0.f, ej1 = 0.f, ej2 = 0.f;

  const float4* CiLo = (const float4*)&Ctab[par * 768];
  const float4* CiHi = (const float4*)&Ctab[par * 768 + 384];
  const float4* CjLo = (const float4*)&Ctab[1536 + par * 768];
  const float4* CjHi = (const float4*)&Ctab[1536 + par * 768 + 384];

  #pragma unroll
  for (int wi = 0; wi < 8; ++wi) {
    const int w = s * 8 + wi;
    const int p = hh * 16 + w;

    float hv[24];
    const float* hp = h + ((size_t)((n * HW + p) * TT)) * VV + v;
    #pragma unroll
    for (int tp = 0; tp < 24; ++tp) hv[tp] = hp[tp * 32];   // coalesced 128B/half-wave

    float dil = 0.f, dih = 0.f, djl = 0.f, djh = 0.f, wh = 0.f;
    #pragma unroll
    for (int q = 0; q < 6; ++q) {
      const float4 cil = CiLo[w * 6 + q], cih = CiHi[w * 6 + q];
      const float4 cjl = CjLo[w * 6 + q], cjh = CjHi[w * 6 + q];
      const float h0 = hv[4*q+0], h1 = hv[4*q+1], h2 = hv[4*q+2], h3 = hv[4*q+3];
      dil += h0*cil.x + h1*cil.y + h2*cil.z + h3*cil.w;
      dih += h0*cih.x + h1*cih.y + h2*cih.z + h3*cih.w;
      djl += h0*cjl.x + h1*cjl.y + h2*cjl.z + h3*cjl.w;
      djh += h0*cjh.x + h1*cjh.y + h2*cjh.z + h3*cjh.w;
      wh  += h0*wcol[4*q+0] + h1*wcol[4*q+1] + h2*wcol[4*q+2] + h3*wcol[4*q+3];
    }
    WhOwnL[p * 32 + v] = wh;   // lanes sweep v: conflict-free

    // bin offsets for this w (0 or 1 relative to base)
    const int offi = ((768 * hh + 24 * w) >> 9) - bi0;
    const int offj = ((768 * hh + 24 * w + 384) >> 9) - bj0;
    ei0 += offi ? 0.f : dil;
    ei1 += offi ? dil : dih;
    ei2 += offi ? dih : 0.f;
    ej0 += offj ? 0.f : djl;
    ej1 += offj ? djl : djh;
    ej2 += offj ? djh : 0.f;
  }

  // one-shot E accumulation (6 atomics/thread, stride-26 rows: 2-way bank alias = free)
  atomicAdd(&EiL[v * 26 + bi0],     ei0);
  atomicAdd(&EiL[v * 26 + bi0 + 1], ei1);
  atomicAdd(&EiL[v * 26 + bi0 + 2], ei2);
  atomicAdd(&EjL[v * 26 + bj0],     ej0);
  atomicAdd(&EjL[v * 26 + bj0 + 1], ej1);
  atomicAdd(&EjL[v * 26 + bj0 + 2], ej2);
  __syncthreads();

  // ---------------- epilogue (Ctab LDS reused) ----------------
  float* adjw = Ctab;          // [i*32+j] -> adj_norm in place
  float* attL = Ctab + 1024;   // [i*32+j] own-t attention
  float* MT   = Ctab + 2048;   // [j*32+v]

  // adjacency + min/max (1024 threads = 1024 cells, one each)
  {
    const int i = tid >> 5, j = tid & 31;
    const float x = Bp[tid] + 1e-6f + (i == j ? 1.f : 0.f);
    adjw[tid] = x;
    float lmn = x, lmx = x;
    #pragma unroll
    for (int off = 32; off > 0; off >>= 1) {
      lmn = fminf(lmn, __shfl_down(lmn, off));
      lmx = fmaxf(lmx, __shfl_down(lmx, off));
    }
    if ((tid & 63) == 0) { redmn[tid >> 6] = lmn; redmx[tid >> 6] = lmx; }
  }
  __syncthreads();
  if (tid == 0) {
    float a0 = redmn[0], b0 = redmx[0];
    #pragma unroll
    for (int k = 1; k < 16; ++k) { a0 = fminf(a0, redmn[k]); b0 = fmaxf(b0, redmx[k]); }
    smn = a0; smx = b0;
  }
  __syncthreads();

  adjw[tid] = (adjw[tid] - smn) * (1.f / (smx - smn));
  __syncthreads();

  if (tid < 32) {
    float sum = 0.f;
    #pragma unroll
    for (int j = 0; j < 32; ++j) sum += adjw[tid * 32 + j];
    dinvL[tid] = rsqrtf(sum);
  }
  __syncthreads();

  adjw[tid] = adjw[tid] * dinvL[tid >> 5] * dinvL[tid & 31];

  // softmax over T for own t (thread = one (i,j) pair)
  {
    const int i = tid >> 5, j = tid & 31;
    const float* Ei = &EiL[i * 26];
    const float* Ej = &EjL[j * 26];
    float ev[24];
    float mx = -1e30f;
    #pragma unroll
    for (int t2 = 0; t2 < 24; ++t2) {
      float x = Ei[t2] + Ej[t2];
      x = x > 0.f ? x : ALPHA * x;          // LeakyReLU
      ev[t2] = x; mx = fmaxf(mx, x);
    }
    float ssum = 0.f;
    #pragma unroll
    for (int t2 = 0; t2 < 24; ++t2) { const float e = __expf(ev[t2] - mx); ev[t2] = e; ssum += e; }
    attL[tid] = ev[t] / ssum;
  }
  __syncthreads();

  // MT[j,v] = sum_i adjn[i,v] * att[i,j]   (thread = one (j,v) cell)
  {
    const int j = tid >> 5, vv = tid & 31;
    float ssum = 0.f;
    #pragma unroll
    for (int i2 = 0; i2 < 32; ++i2) ssum += adjw[i2 * 32 + vv] * attL[i2 * 32 + j];
    MT[tid] = ssum;
  }
  __syncthreads();

  // out[p,t,v] = sigmoid(elu( sum_j WhOwn[p,j] * MT[j,v] ))
  float mv[32];
  #pragma unroll
  for (int jj = 0; jj < 32; ++jj) mv[jj] = MT[jj * 32 + v];   // conflict-free

  const int g2 = tid >> 5;   // 0..31
  float* outg = out + (size_t)n * HW * TT * VV + (size_t)t * VV + v;
  #pragma unroll
  for (int k = 0; k < 8; ++k) {
    const int p = g2 * 8 + k;
    const float4* wr = (const float4*)&WhOwnL[p * 32];   // broadcast b128 reads
    float accv = 0.f;
    #pragma unroll
    for (int q = 0; q < 8; ++q) {
      float4 w4 = wr[q];
      accv += w4.x * mv[q*4+0] + w4.y * mv[q*4+1] + w4.z * mv[q*4+2] + w4.w * mv[q*4+3];
    }
    const float e  = accv > 0.f ? accv : (__expf(accv) - 1.f);  // ELU(alpha=1)
    const float sg = 1.f / (1.f + __expf(-e));                  // sigmoid
    outg[(size_t)p * TT * VV] = sg;
  }
}

// ---------------------------------------------------------------------------
extern "C" void kernel_launch(void* const* d_in, const int* in_sizes, int n_in,
                              void* d_out, int out_size, void* d_ws, size_t ws_size,
                              hipStream_t stream) {
  const float* h  = (const float*)d_in[0];   // (4,16,16,24,32) f32
  const float* Wp = (const float*)d_in[1];   // (24,24)
  const float* ap = (const float*)d_in[2];   // (512,1)
  const float* Bp = (const float*)d_in[3];   // (32,32)
  float* out = (float*)d_out;                // (4,16,16,24,32) f32
  (void)d_ws; (void)ws_size;                 // no scratch: no handoff/flush tax

  hipLaunchKernelGGL(gat_one, dim3(NB * TT), dim3(1024), 0, stream,
                     h, Wp, ap, Bp, out);
}